// Round 1
// baseline (260.228 us; speedup 1.0000x reference)
//
#include <hip/hip_runtime.h>
#include <math.h>

// LSTMLightweight on MI355X:
//   x[B,T,1] -> linear_in(1->16)+ReLU -> LSTM0(16) -> LSTM1(16) -> fc(16->8)+ReLU -> fc(8->1)
// Fused single kernel. 16 threads per batch element (thread j owns hidden unit j:
// gate rows j,16+j,32+j,48+j), 4 elements per 64-thread (1-wave) block.
// Recurrent weights live in VGPRs; h-vectors exchanged through small padded LDS
// buffers (pad rows to 20 f32 -> max 2-way bank aliasing, free on CDNA4).
// linear_in+ReLU+w_ih0 collapses to x * (x>0 ? Ap : An) when lin_in_b == 0
// (true for this benchmark's inputs); a general fallback path (cooperative xi +
// LDS-resident w_ih0) handles nonzero bias without costing fast-path registers.

#define EPW 4
#define TCHUNK 256
#define L2E 1.4426950408889634f

__device__ __forceinline__ float sigm(float v) {
    return __builtin_amdgcn_rcpf(1.0f + __builtin_amdgcn_exp2f(-L2E * v));
}
__device__ __forceinline__ float tanh_(float v) {
    // tanh(v) = 1 - 2/(exp(2v)+1); saturates correctly at +-inf
    return 1.0f - 2.0f * __builtin_amdgcn_rcpf(1.0f + __builtin_amdgcn_exp2f((2.0f * L2E) * v));
}

#define DOT16(ACC, W, BUFROW)                                          \
    _Pragma("unroll")                                                  \
    for (int c = 0; c < 4; ++c) {                                      \
        float4 hv = (BUFROW)[c];                                       \
        _Pragma("unroll")                                              \
        for (int g = 0; g < 4; ++g) {                                  \
            ACC[g] = fmaf(W[g][4 * c + 0], hv.x, ACC[g]);              \
            ACC[g] = fmaf(W[g][4 * c + 1], hv.y, ACC[g]);              \
            ACC[g] = fmaf(W[g][4 * c + 2], hv.z, ACC[g]);              \
            ACC[g] = fmaf(W[g][4 * c + 3], hv.w, ACC[g]);              \
        }                                                              \
    }

__global__ __launch_bounds__(64, 2) void lstm_fused(
    const float* __restrict__ x,
    const float* __restrict__ w_in, const float* __restrict__ b_in,
    const float* __restrict__ w_ih0, const float* __restrict__ w_hh0,
    const float* __restrict__ b_ih0, const float* __restrict__ b_hh0,
    const float* __restrict__ w_ih1, const float* __restrict__ w_hh1,
    const float* __restrict__ b_ih1, const float* __restrict__ b_hh1,
    const float* __restrict__ fc_h_w, const float* __restrict__ fc_h_b,
    const float* __restrict__ fc_o_w, const float* __restrict__ fc_o_b,
    float* __restrict__ out, int B, int T)
{
    const int lane = threadIdx.x;      // 0..63
    const int e    = lane >> 4;        // local element 0..3
    const int j    = lane & 15;        // hidden unit 0..15
    const int elem  = blockIdx.x * EPW + e;
    const int elemc = elem < B ? elem : B - 1;

    __shared__ float  xs[EPW][TCHUNK + 4];
    __shared__ float4 h0b[EPW][5];     // 20 f32 per row (padded)
    __shared__ float4 h1b[EPW][5];
    __shared__ float  wih0s[64][20];   // fallback path only
    __shared__ float  zb[EPW][20];     // fc-z exchange; xi exchange in fallback

    // ---- one-time weight preload into registers ----
    float whh0r[4][16], wih1r[4][16], whh1r[4][16];
    float b0[4], b1[4], ap[4], an[4];
    #pragma unroll
    for (int g = 0; g < 4; ++g) {
        const int row = g * 16 + j;
        #pragma unroll
        for (int k = 0; k < 16; ++k) {
            whh0r[g][k] = w_hh0[row * 16 + k];
            wih1r[g][k] = w_ih1[row * 16 + k];
            whh1r[g][k] = w_hh1[row * 16 + k];
        }
        b0[g] = b_ih0[row] + b_hh0[row];
        b1[g] = b_ih1[row] + b_hh1[row];
        ap[g] = 0.0f; an[g] = 0.0f;
    }
    // Fold linear_in(+ReLU) through w_ih0 for the b_in==0 case:
    //   x>0: contribution = x * sum_k w_ih0[row][k]*max(w_in[k],0)   (=Ap)
    //   x<0: contribution = x * sum_k w_ih0[row][k]*min(w_in[k],0)   (=An)
    bool bzero = true;
    #pragma unroll
    for (int k = 0; k < 16; ++k) {
        const float wk = w_in[k];
        if (b_in[k] != 0.0f) bzero = false;
        const float wp = fmaxf(wk, 0.0f), wn = fminf(wk, 0.0f);
        #pragma unroll
        for (int g = 0; g < 4; ++g) {
            const float wg = w_ih0[(g * 16 + j) * 16 + k];
            ap[g] = fmaf(wg, wp, ap[g]);
            an[g] = fmaf(wg, wn, an[g]);
        }
    }
    const float winj = w_in[j], binj = b_in[j];
    if (!bzero) {  // stage w_ih0 to LDS for the general path
        for (int idx = lane; idx < 1024; idx += 64)
            wih0s[idx >> 4][idx & 15] = w_ih0[idx];
    }

    // ---- zero state ----
    ((float*)&h0b[e][0])[j] = 0.0f;
    ((float*)&h1b[e][0])[j] = 0.0f;
    float c0 = 0.0f, c1 = 0.0f;

    const float* xrow = x + (size_t)elemc * T;

    for (int tb = 0; tb < T; tb += TCHUNK) {
        const int tc = (T - tb) < TCHUNK ? (T - tb) : TCHUNK;
        __syncthreads();
        for (int tt = j; tt < tc; tt += 16) xs[e][tt] = xrow[tb + tt];
        __syncthreads();

        if (bzero) {
            for (int tt = 0; tt < tc; ++tt) {
                const float xv = xs[e][tt];
                float a[4];
                const bool xp = xv > 0.0f;
                #pragma unroll
                for (int g = 0; g < 4; ++g) a[g] = fmaf(xv, xp ? ap[g] : an[g], b0[g]);
                DOT16(a, whh0r, h0b[e]);                 // + h0_{t-1} @ w_hh0^T
                float ig = sigm(a[0]), fg = sigm(a[1]), gv = tanh_(a[2]), og = sigm(a[3]);
                c0 = fmaf(fg, c0, ig * gv);
                const float h0j = og * tanh_(c0);
                __syncthreads();
                ((float*)&h0b[e][0])[j] = h0j;
                __syncthreads();
                // layer 1
                #pragma unroll
                for (int g = 0; g < 4; ++g) a[g] = b1[g];
                DOT16(a, wih1r, h0b[e]);                 // h0_t @ w_ih1^T
                DOT16(a, whh1r, h1b[e]);                 // h1_{t-1} @ w_hh1^T
                ig = sigm(a[0]); fg = sigm(a[1]); gv = tanh_(a[2]); og = sigm(a[3]);
                c1 = fmaf(fg, c1, ig * gv);
                const float h1j = og * tanh_(c1);
                __syncthreads();
                ((float*)&h1b[e][0])[j] = h1j;
                __syncthreads();
            }
        } else {
            // general path: cooperative xi + LDS-resident w_ih0 (never taken in
            // this benchmark; kept register-cheap on purpose)
            for (int tt = 0; tt < tc; ++tt) {
                const float xv = xs[e][tt];
                const float xi = fmaxf(fmaf(xv, winj, binj), 0.0f);
                __syncthreads();
                zb[e][j] = xi;
                __syncthreads();
                float a[4];
                #pragma unroll
                for (int g = 0; g < 4; ++g) a[g] = b0[g];
                #pragma unroll
                for (int c = 0; c < 4; ++c) {
                    const float4 xiv = *(const float4*)&zb[e][4 * c];
                    #pragma unroll
                    for (int g = 0; g < 4; ++g) {
                        const float4 wv = *(const float4*)&wih0s[g * 16 + j][4 * c];
                        a[g] = fmaf(wv.x, xiv.x, a[g]);
                        a[g] = fmaf(wv.y, xiv.y, a[g]);
                        a[g] = fmaf(wv.z, xiv.z, a[g]);
                        a[g] = fmaf(wv.w, xiv.w, a[g]);
                    }
                }
                DOT16(a, whh0r, h0b[e]);
                float ig = sigm(a[0]), fg = sigm(a[1]), gv = tanh_(a[2]), og = sigm(a[3]);
                c0 = fmaf(fg, c0, ig * gv);
                const float h0j = og * tanh_(c0);
                __syncthreads();
                ((float*)&h0b[e][0])[j] = h0j;
                __syncthreads();
                #pragma unroll
                for (int g = 0; g < 4; ++g) a[g] = b1[g];
                DOT16(a, wih1r, h0b[e]);
                DOT16(a, whh1r, h1b[e]);
                ig = sigm(a[0]); fg = sigm(a[1]); gv = tanh_(a[2]); og = sigm(a[3]);
                c1 = fmaf(fg, c1, ig * gv);
                const float h1j = og * tanh_(c1);
                __syncthreads();
                ((float*)&h1b[e][0])[j] = h1j;
                __syncthreads();
            }
        }
    }

    // ---- head: fc_h (16->8) + ReLU, fc_o (8->1) ----
    __syncthreads();
    if (j < 8) {
        float acc = fc_h_b[j];
        const float* h1p = (const float*)&h1b[e][0];
        #pragma unroll
        for (int k = 0; k < 16; ++k) acc = fmaf(fc_h_w[j * 16 + k], h1p[k], acc);
        zb[e][j] = fmaxf(acc, 0.0f);
    }
    __syncthreads();
    if (j == 0 && elem < B) {
        float acc = fc_o_b[0];
        #pragma unroll
        for (int r = 0; r < 8; ++r) acc = fmaf(fc_o_w[r], zb[e][r], acc);
        out[elem] = acc;
    }
}

extern "C" void kernel_launch(void* const* d_in, const int* in_sizes, int n_in,
                              void* d_out, int out_size, void* d_ws, size_t ws_size,
                              hipStream_t stream) {
    const float* x      = (const float*)d_in[0];
    const float* w_in   = (const float*)d_in[1];
    const float* b_in   = (const float*)d_in[2];
    const float* w_ih0  = (const float*)d_in[3];
    const float* w_hh0  = (const float*)d_in[4];
    const float* b_ih0  = (const float*)d_in[5];
    const float* b_hh0  = (const float*)d_in[6];
    const float* w_ih1  = (const float*)d_in[7];
    const float* w_hh1  = (const float*)d_in[8];
    const float* b_ih1  = (const float*)d_in[9];
    const float* b_hh1  = (const float*)d_in[10];
    const float* fc_h_w = (const float*)d_in[11];
    const float* fc_h_b = (const float*)d_in[12];
    const float* fc_o_w = (const float*)d_in[13];
    const float* fc_o_b = (const float*)d_in[14];

    const int B = out_size;                 // x is [B,T,1]
    const int T = in_sizes[0] / (B > 0 ? B : 1);
    const int grid = (B + EPW - 1) / EPW;

    hipLaunchKernelGGL(lstm_fused, dim3(grid), dim3(64), 0, stream,
                       x, w_in, b_in, w_ih0, w_hh0, b_ih0, b_hh0,
                       w_ih1, w_hh1, b_ih1, b_hh1, fc_h_w, fc_h_b,
                       fc_o_w, fc_o_b, (float*)d_out, B, T);
}

// Round 2
// 233.659 us; speedup vs baseline: 1.1137x; 1.1137x over previous
//
#include <hip/hip_runtime.h>
#include <math.h>

// LSTMLightweight on MI355X:
//   x[B,T,1] -> linear_in(1->16)+ReLU -> LSTM0(16) -> LSTM1(16) -> fc(16->8)+ReLU -> fc(8->1)
// Fused single kernel. 16 threads per batch element (thread j owns hidden unit j:
// gate rows j,16+j,32+j,48+j), 4 elements per 64-thread (1-wave) block.
// Recurrent weights live in VGPRs as f32 pairs -> v_pk_fma_f32 (2 FLOP/instr).
// h-vectors exchanged through small padded LDS buffers.
// R2 changes vs R1: amdgpu_waves_per_eu(2,2) pins the VGPR budget at 256
// (R1's allocator targeted 4 waves/EU at 128 VGPR and spilled ~24MB/call),
// and all dots use packed-f32 FMA to halve VALU instruction count.

#define EPW 4
#define TCHUNK 256
#define L2E 1.4426950408889634f

typedef float v2f __attribute__((ext_vector_type(2)));

__device__ __forceinline__ float sigm(float v) {
    return __builtin_amdgcn_rcpf(1.0f + __builtin_amdgcn_exp2f(-L2E * v));
}
__device__ __forceinline__ float tanh_(float v) {
    // tanh(v) = 1 - 2/(exp(2v)+1); saturates correctly at +-inf
    return 1.0f - 2.0f * __builtin_amdgcn_rcpf(1.0f + __builtin_amdgcn_exp2f((2.0f * L2E) * v));
}

// packed dot: ACC[g] (v2f, even/odd partial sums) += row_g(W2) . h(BUFROW)
#define DOTP(ACC, W2, BUFROW)                                                   \
    _Pragma("unroll")                                                           \
    for (int c = 0; c < 4; ++c) {                                               \
        float4 hv = (BUFROW)[c];                                                \
        v2f hlo = {hv.x, hv.y};                                                 \
        v2f hhi = {hv.z, hv.w};                                                 \
        _Pragma("unroll")                                                       \
        for (int g = 0; g < 4; ++g) {                                           \
            ACC[g] = __builtin_elementwise_fma(W2[g][2 * c], hlo, ACC[g]);      \
            ACC[g] = __builtin_elementwise_fma(W2[g][2 * c + 1], hhi, ACC[g]);  \
        }                                                                       \
    }

__global__ __launch_bounds__(64) __attribute__((amdgpu_waves_per_eu(2, 2)))
void lstm_fused(
    const float* __restrict__ x,
    const float* __restrict__ w_in, const float* __restrict__ b_in,
    const float* __restrict__ w_ih0, const float* __restrict__ w_hh0,
    const float* __restrict__ b_ih0, const float* __restrict__ b_hh0,
    const float* __restrict__ w_ih1, const float* __restrict__ w_hh1,
    const float* __restrict__ b_ih1, const float* __restrict__ b_hh1,
    const float* __restrict__ fc_h_w, const float* __restrict__ fc_h_b,
    const float* __restrict__ fc_o_w, const float* __restrict__ fc_o_b,
    float* __restrict__ out, int B, int T)
{
    const int lane = threadIdx.x;      // 0..63
    const int e    = lane >> 4;        // local element 0..3
    const int j    = lane & 15;        // hidden unit 0..15
    const int elem  = blockIdx.x * EPW + e;
    const int elemc = elem < B ? elem : B - 1;

    __shared__ float  xs[EPW][TCHUNK + 8];  // row stride 1056B -> 16B-aligned
    __shared__ float4 h0b[EPW][5];          // 20 f32 per row (padded)
    __shared__ float4 h1b[EPW][5];
    __shared__ float  wih0s[64][20];        // fallback path only
    __shared__ float  zb[EPW][20];          // fc-z exchange; xi exchange in fallback

    // ---- one-time weight preload into registers (packed pairs) ----
    v2f whh0r[4][8], wih1r[4][8], whh1r[4][8];
    float b0[4], b1[4], ap[4], an[4];
    #pragma unroll
    for (int g = 0; g < 4; ++g) {
        const int row = g * 16 + j;
        #pragma unroll
        for (int p = 0; p < 8; ++p) {
            whh0r[g][p] = (v2f){w_hh0[row * 16 + 2 * p], w_hh0[row * 16 + 2 * p + 1]};
            wih1r[g][p] = (v2f){w_ih1[row * 16 + 2 * p], w_ih1[row * 16 + 2 * p + 1]};
            whh1r[g][p] = (v2f){w_hh1[row * 16 + 2 * p], w_hh1[row * 16 + 2 * p + 1]};
        }
        b0[g] = b_ih0[row] + b_hh0[row];
        b1[g] = b_ih1[row] + b_hh1[row];
        ap[g] = 0.0f; an[g] = 0.0f;
    }
    // Fold linear_in(+ReLU) through w_ih0 for the b_in==0 case:
    //   x>0: contribution = x * sum_k w_ih0[row][k]*max(w_in[k],0)   (=Ap)
    //   x<0: contribution = x * sum_k w_ih0[row][k]*min(w_in[k],0)   (=An)
    bool bzero = true;
    #pragma unroll
    for (int k = 0; k < 16; ++k) {
        const float wk = w_in[k];
        if (b_in[k] != 0.0f) bzero = false;
        const float wp = fmaxf(wk, 0.0f), wn = fminf(wk, 0.0f);
        #pragma unroll
        for (int g = 0; g < 4; ++g) {
            const float wg = w_ih0[(g * 16 + j) * 16 + k];
            ap[g] = fmaf(wg, wp, ap[g]);
            an[g] = fmaf(wg, wn, an[g]);
        }
    }
    const float winj = w_in[j], binj = b_in[j];
    if (!bzero) {  // stage w_ih0 to LDS for the general path
        for (int idx = lane; idx < 1024; idx += 64)
            wih0s[idx >> 4][idx & 15] = w_ih0[idx];
    }

    // ---- zero state ----
    ((float*)&h0b[e][0])[j] = 0.0f;
    ((float*)&h1b[e][0])[j] = 0.0f;
    float c0 = 0.0f, c1 = 0.0f;

    const float* xrow = x + (size_t)elemc * T;

    for (int tb = 0; tb < T; tb += TCHUNK) {
        const int tc = (T - tb) < TCHUNK ? (T - tb) : TCHUNK;
        __syncthreads();
        if ((tc & 63) == 0) {   // vectorized x staging (T=256 path)
            for (int tt = 4 * j; tt < tc; tt += 64)
                *(float4*)&xs[e][tt] = *(const float4*)&xrow[tb + tt];
        } else {
            for (int tt = j; tt < tc; tt += 16) xs[e][tt] = xrow[tb + tt];
        }
        __syncthreads();

        if (bzero) {
            for (int tt = 0; tt < tc; ++tt) {
                const float xv = xs[e][tt];
                const bool xp = xv > 0.0f;
                v2f acc[4];
                #pragma unroll
                for (int g = 0; g < 4; ++g)
                    acc[g] = (v2f){fmaf(xv, xp ? ap[g] : an[g], b0[g]), 0.0f};
                DOTP(acc, whh0r, h0b[e]);                 // + h0_{t-1} @ w_hh0^T
                float ig = sigm(acc[0][0] + acc[0][1]);
                float fg = sigm(acc[1][0] + acc[1][1]);
                float gv = tanh_(acc[2][0] + acc[2][1]);
                float og = sigm(acc[3][0] + acc[3][1]);
                c0 = fmaf(fg, c0, ig * gv);
                const float h0j = og * tanh_(c0);
                __syncthreads();
                ((float*)&h0b[e][0])[j] = h0j;
                __syncthreads();
                // layer 1
                #pragma unroll
                for (int g = 0; g < 4; ++g) acc[g] = (v2f){b1[g], 0.0f};
                DOTP(acc, wih1r, h0b[e]);                 // h0_t @ w_ih1^T
                DOTP(acc, whh1r, h1b[e]);                 // h1_{t-1} @ w_hh1^T
                ig = sigm(acc[0][0] + acc[0][1]);
                fg = sigm(acc[1][0] + acc[1][1]);
                gv = tanh_(acc[2][0] + acc[2][1]);
                og = sigm(acc[3][0] + acc[3][1]);
                c1 = fmaf(fg, c1, ig * gv);
                const float h1j = og * tanh_(c1);
                __syncthreads();
                ((float*)&h1b[e][0])[j] = h1j;
                __syncthreads();
            }
        } else {
            // general path: cooperative xi + LDS-resident w_ih0 (never taken in
            // this benchmark; kept register-cheap on purpose)
            for (int tt = 0; tt < tc; ++tt) {
                const float xv = xs[e][tt];
                const float xi = fmaxf(fmaf(xv, winj, binj), 0.0f);
                __syncthreads();
                zb[e][j] = xi;
                __syncthreads();
                v2f acc[4];
                #pragma unroll
                for (int g = 0; g < 4; ++g) acc[g] = (v2f){b0[g], 0.0f};
                #pragma unroll
                for (int c = 0; c < 4; ++c) {
                    const float4 xiv = *(const float4*)&zb[e][4 * c];
                    #pragma unroll
                    for (int g = 0; g < 4; ++g) {
                        const float4 wv = *(const float4*)&wih0s[g * 16 + j][4 * c];
                        acc[g][0] = fmaf(wv.x, xiv.x, acc[g][0]);
                        acc[g][1] = fmaf(wv.y, xiv.y, acc[g][1]);
                        acc[g][0] = fmaf(wv.z, xiv.z, acc[g][0]);
                        acc[g][1] = fmaf(wv.w, xiv.w, acc[g][1]);
                    }
                }
                DOTP(acc, whh0r, h0b[e]);
                float ig = sigm(acc[0][0] + acc[0][1]);
                float fg = sigm(acc[1][0] + acc[1][1]);
                float gv = tanh_(acc[2][0] + acc[2][1]);
                float og = sigm(acc[3][0] + acc[3][1]);
                c0 = fmaf(fg, c0, ig * gv);
                const float h0j = og * tanh_(c0);
                __syncthreads();
                ((float*)&h0b[e][0])[j] = h0j;
                __syncthreads();
                #pragma unroll
                for (int g = 0; g < 4; ++g) acc[g] = (v2f){b1[g], 0.0f};
                DOTP(acc, wih1r, h0b[e]);
                DOTP(acc, whh1r, h1b[e]);
                ig = sigm(acc[0][0] + acc[0][1]);
                fg = sigm(acc[1][0] + acc[1][1]);
                gv = tanh_(acc[2][0] + acc[2][1]);
                og = sigm(acc[3][0] + acc[3][1]);
                c1 = fmaf(fg, c1, ig * gv);
                const float h1j = og * tanh_(c1);
                __syncthreads();
                ((float*)&h1b[e][0])[j] = h1j;
                __syncthreads();
            }
        }
    }

    // ---- head: fc_h (16->8) + ReLU, fc_o (8->1) ----
    __syncthreads();
    if (j < 8) {
        float acc = fc_h_b[j];
        const float* h1p = (const float*)&h1b[e][0];
        #pragma unroll
        for (int k = 0; k < 16; ++k) acc = fmaf(fc_h_w[j * 16 + k], h1p[k], acc);
        zb[e][j] = fmaxf(acc, 0.0f);
    }
    __syncthreads();
    if (j == 0 && elem < B) {
        float acc = fc_o_b[0];
        #pragma unroll
        for (int r = 0; r < 8; ++r) acc = fmaf(fc_o_w[r], zb[e][r], acc);
        out[elem] = acc;
    }
}

extern "C" void kernel_launch(void* const* d_in, const int* in_sizes, int n_in,
                              void* d_out, int out_size, void* d_ws, size_t ws_size,
                              hipStream_t stream) {
    const float* x      = (const float*)d_in[0];
    const float* w_in   = (const float*)d_in[1];
    const float* b_in   = (const float*)d_in[2];
    const float* w_ih0  = (const float*)d_in[3];
    const float* w_hh0  = (const float*)d_in[4];
    const float* b_ih0  = (const float*)d_in[5];
    const float* b_hh0  = (const float*)d_in[6];
    const float* w_ih1  = (const float*)d_in[7];
    const float* w_hh1  = (const float*)d_in[8];
    const float* b_ih1  = (const float*)d_in[9];
    const float* b_hh1  = (const float*)d_in[10];
    const float* fc_h_w = (const float*)d_in[11];
    const float* fc_h_b = (const float*)d_in[12];
    const float* fc_o_w = (const float*)d_in[13];
    const float* fc_o_b = (const float*)d_in[14];

    const int B = out_size;                 // x is [B,T,1]
    const int T = in_sizes[0] / (B > 0 ? B : 1);
    const int grid = (B + EPW - 1) / EPW;

    hipLaunchKernelGGL(lstm_fused, dim3(grid), dim3(64), 0, stream,
                       x, w_in, b_in, w_ih0, w_hh0, b_ih0, b_hh0,
                       w_ih1, w_hh1, b_ih1, b_hh1, fc_h_w, fc_h_b,
                       fc_o_w, fc_o_b, (float*)d_out, B, T);
}